// Round 14
// baseline (138.117 us; speedup 1.0000x reference)
//
#include <hip/hip_runtime.h>

#define N_ROWS 8192
#define IN_DIM 1024
#define KF     8

typedef _Float16 half8 __attribute__((ext_vector_type(8)));
typedef _Float16 half4 __attribute__((ext_vector_type(4)));
typedef float    floatx4 __attribute__((ext_vector_type(4)));
typedef float    floatx16 __attribute__((ext_vector_type(16)));
typedef int      intx4  __attribute__((ext_vector_type(4)));
typedef int      intx16 __attribute__((ext_vector_type(16)));

__device__ __forceinline__ half8 ld_half8(const _Float16* p) {
    int4 t = *(const int4*)p;
    return __builtin_bit_cast(half8, t);
}
__device__ __forceinline__ void fsplit(float v, _Float16& h, _Float16& l) {
    _Float16 x = (_Float16)v;
    h = x;
    l = (_Float16)((v - (float)x) * 2048.0f);
}
__device__ __forceinline__ void gload16(const void* g, void* l) {
    __builtin_amdgcn_global_load_lds(
        (const __attribute__((address_space(1))) void*)g,
        (__attribute__((address_space(3))) void*)l,
        16, 0, 0);
}

// ---------------------------------------------------------------------------
// pass 1: ONE coalesced read of x -> per-row idx + byte-packed xB[8192][1024]
__global__ __launch_bounds__(256) void pack_extract(const int* __restrict__ x,
                                                    int* __restrict__ idx,
                                                    char* __restrict__ xB) {
    const int r    = blockIdx.x * 4 + (threadIdx.x >> 6);
    const int lane = threadIdx.x & 63;
    const int* row = x + (size_t)r * IN_DIM;

    int vals[16];
    #pragma unroll
    for (int j = 0; j < 4; ++j) {
        int4 v = ((const int4*)row)[lane * 4 + j];
        vals[j * 4 + 0] = v.x;
        vals[j * 4 + 1] = v.y;
        vals[j * 4 + 2] = v.z;
        vals[j * 4 + 3] = v.w;
    }
    int4 pk;
    int* pw = &pk.x;
    #pragma unroll
    for (int g = 0; g < 4; ++g) {
        pw[g] = (vals[g * 4 + 0] & 1) | ((vals[g * 4 + 1] & 1) << 8)
              | ((vals[g * 4 + 2] & 1) << 16) | ((vals[g * 4 + 3] & 1) << 24);
    }
    *(int4*)&xB[(size_t)r * 1024 + lane * 16] = pk;

    int c = 0;
    #pragma unroll
    for (int j = 0; j < 16; ++j) c += (vals[j] != 0);
    int s = c;
    #pragma unroll
    for (int o = 1; o < 64; o <<= 1) {
        int t = __shfl_up(s, o, 64);
        if (lane >= o) s += t;
    }
    int pos = s - c;
    #pragma unroll
    for (int j = 0; j < 16; ++j) {
        if (vals[j] != 0) {
            if (pos < KF) idx[r * KF + pos] = lane * 16 + j;
            pos++;
        }
    }
}

// ---------------------------------------------------------------------------
// prepT: role = blockIdx.y
//  0: byte transpose xB -> xT   1: split E   2: split W2
//  3: transp-split W1           4: transp-split W3
__global__ __launch_bounds__(256) void prepT(
        const char* __restrict__ xB, char* __restrict__ xT,
        const float* __restrict__ emb, const float* __restrict__ W1,
        const float* __restrict__ W2, const float* __restrict__ W3,
        _Float16* __restrict__ Eh, _Float16* __restrict__ El,
        _Float16* __restrict__ W1th, _Float16* __restrict__ W1tl,
        _Float16* __restrict__ W2h, _Float16* __restrict__ W2l,
        _Float16* __restrict__ W3th, _Float16* __restrict__ W3tl) {
    const int role = blockIdx.y;
    const int bx   = blockIdx.x;

    if (role == 0) {           // transpose8 (proven)
        __shared__ char t[64][144];
        const int r0 = (bx & 63) << 7;
        const int c0 = (bx >> 6) << 6;
        const int rg = threadIdx.x >> 4;
        const int cg = threadIdx.x & 15;

        int v[8];
        #pragma unroll
        for (int p = 0; p < 8; ++p)
            v[p] = *(const int*)&xB[(size_t)(r0 + rg * 8 + p) * 1024 + c0 + cg * 4];

        #pragma unroll
        for (int tt = 0; tt < 4; ++tt) {
            const int sh = tt * 8;
            unsigned lo = ((unsigned)(v[0] >> sh) & 0xffu)
                        | (((unsigned)(v[1] >> sh) & 0xffu) << 8)
                        | (((unsigned)(v[2] >> sh) & 0xffu) << 16)
                        | (((unsigned)(v[3] >> sh) & 0xffu) << 24);
            unsigned hi = ((unsigned)(v[4] >> sh) & 0xffu)
                        | (((unsigned)(v[5] >> sh) & 0xffu) << 8)
                        | (((unsigned)(v[6] >> sh) & 0xffu) << 16)
                        | (((unsigned)(v[7] >> sh) & 0xffu) << 24);
            int2 pk = make_int2((int)lo, (int)hi);
            *(int2*)&t[cg * 4 + tt][rg * 8] = pk;
        }
        __syncthreads();

        const int col = threadIdx.x >> 2;
        const int pt  = (threadIdx.x & 3) << 5;
        int4 o0 = *(const int4*)&t[col][pt];
        int4 o1 = *(const int4*)&t[col][pt + 16];
        char* dst = &xT[(size_t)(c0 + col) * 8192 + r0 + pt];
        *(int4*)dst = o0;
        *(int4*)(dst + 16) = o1;
        return;
    }

    const int task = role - 1;
    if (task <= 1) {           // natural split (proven)
        const float* S = task ? W2 : emb;
        _Float16* Hp = task ? W2h : Eh;
        _Float16* Lp = task ? W2l : El;
        size_t i = ((size_t)bx * 256 + threadIdx.x) << 2;
        float4 v = *(const float4*)&S[i];
        float vv[4] = {v.x, v.y, v.z, v.w};
        half4 h, l;
        #pragma unroll
        for (int j = 0; j < 4; ++j) { _Float16 hh, ll; fsplit(vv[j], hh, ll); h[j] = hh; l[j] = ll; }
        *(int2*)&Hp[i] = __builtin_bit_cast(int2, h);
        *(int2*)&Lp[i] = __builtin_bit_cast(int2, l);
        return;
    }
    if (bx >= 256) return;     // transposed split (proven)
    const float* S = (task == 3) ? W3 : W1;
    _Float16* Hp = (task == 3) ? W3th : W1th;
    _Float16* Lp = (task == 3) ? W3tl : W1tl;
    __shared__ float sh[64][65];
    const int r0 = (bx >> 4) << 6, c0 = (bx & 15) << 6;
    #pragma unroll
    for (int it = 0; it < 4; ++it) {
        int r = (threadIdx.x >> 4) + (it << 4);
        int c = (threadIdx.x & 15) << 2;
        float4 v = *(const float4*)&S[(size_t)(r0 + r) * 1024 + c0 + c];
        sh[r][c] = v.x; sh[r][c + 1] = v.y; sh[r][c + 2] = v.z; sh[r][c + 3] = v.w;
    }
    __syncthreads();
    int nl = threadIdx.x >> 2;
    #pragma unroll
    for (int cc = 0; cc < 2; ++cc) {
        int kq = ((threadIdx.x & 3) << 4) + (cc << 3);
        half8 h, l;
        #pragma unroll
        for (int j = 0; j < 8; ++j) {
            _Float16 hh, ll;
            fsplit(sh[kq + j][nl], hh, ll);
            h[j] = hh; l[j] = ll;
        }
        *(int4*)&Hp[(size_t)(c0 + nl) * 1024 + r0 + kq] = __builtin_bit_cast(int4, h);
        *(int4*)&Lp[(size_t)(c0 + nl) * 1024 + r0 + kq] = __builtin_bit_cast(int4, l);
    }
}

// ---------------------------------------------------------------------------
struct GemmDesc {
    const _Float16 *Ah, *Al;
    const _Float16 *Bh, *Bl;
    float* Df;
    _Float16 *Dnh, *Dnl;
    _Float16 *Dth, *Dtl;
};

// proven split-f16 MFMA GEMM body (64x64, 4 waves, 32x32x16, 3 chains)
__device__ __forceinline__ void gemm_body(GemmDesc d, char* smem_, int bx, int by) {
    _Float16 (*lds)[4][64][64] = (_Float16 (*)[4][64][64])smem_;

    const int tid  = threadIdx.x;
    const int lane = tid & 63;
    const int w    = tid >> 6;
    const int wm   = w >> 1, wn = w & 1;
    const int brow = by << 6;
    const int bcol = bx << 6;

    const _Float16* gsrc = (w == 0) ? d.Ah : (w == 1) ? d.Al : (w == 2) ? d.Bh : d.Bl;
    const int rowbase = (w < 2) ? brow : bcol;
    const int swz = (((lane & 7) ^ ((lane >> 3) & 7)) << 3);
    const _Float16* gbase = gsrc + (size_t)(rowbase + (lane >> 3)) * 1024 + swz;

#define STAGE(kt_, buf_) do {                                              \
        _Float16* lb = &lds[buf_][w][0][0];                                \
        const _Float16* gb = gbase + ((kt_) << 6);                         \
        _Pragma("unroll")                                                  \
        for (int c = 0; c < 8; ++c)                                        \
            gload16(gb + ((size_t)(c << 3) << 10), lb + (c << 9));         \
    } while (0)

    const int l31  = lane & 31;
    const int kh   = lane >> 5;
    const int arow = (wm << 5) + l31;
    const int brw  = (wn << 5) + l31;
    const int r7   = l31 & 7;

    floatx16 acc0 = {};
    floatx16 acc1 = {};
    floatx16 acc2 = {};

    STAGE(0, 0);
    __syncthreads();

    int cur = 0;
    for (int kt = 0; kt < 16; ++kt) {
        if (kt < 15) STAGE(kt + 1, cur ^ 1);
        const _Float16* pa_h = &lds[cur][0][arow][0];
        const _Float16* pa_l = &lds[cur][1][arow][0];
        const _Float16* pb_h = &lds[cur][2][brw][0];
        const _Float16* pb_l = &lds[cur][3][brw][0];
        #pragma unroll
        for (int kc = 0; kc < 4; ++kc) {
            int ca = ((((kc << 1) | kh) ^ r7) << 3);
            half8 ah = ld_half8(pa_h + ca);
            half8 al = ld_half8(pa_l + ca);
            half8 bh = ld_half8(pb_h + ca);
            half8 bl = ld_half8(pb_l + ca);
            acc0 = __builtin_amdgcn_mfma_f32_32x32x16_f16(ah, bh, acc0, 0, 0, 0);
            acc1 = __builtin_amdgcn_mfma_f32_32x32x16_f16(ah, bl, acc1, 0, 0, 0);
            acc2 = __builtin_amdgcn_mfma_f32_32x32x16_f16(al, bh, acc2, 0, 0, 0);
        }
        if (kt < 15) {
            __syncthreads();
            cur ^= 1;
        }
    }
#undef STAGE

    const float is = 1.0f / 2048.0f;
    const int grow = brow + (wm << 5) + (kh << 2);
    const int gcol = bcol + (wn << 5) + l31;

    if (d.Df) {
        #pragma unroll
        for (int r = 0; r < 16; ++r) {
            int row = grow + (r & 3) + ((r >> 2) << 3);
            d.Df[(size_t)row * 1024 + gcol] = acc0[r] + (acc1[r] + acc2[r]) * is;
        }
    }
    if (d.Dnh) {
        #pragma unroll
        for (int r = 0; r < 16; ++r) {
            int row = grow + (r & 3) + ((r >> 2) << 3);
            _Float16 h, l;
            fsplit(acc0[r] + (acc1[r] + acc2[r]) * is, h, l);
            d.Dnh[(size_t)row * 1024 + gcol] = h;
            d.Dnl[(size_t)row * 1024 + gcol] = l;
        }
    }
    if (d.Dth) {
        #pragma unroll
        for (int g = 0; g < 4; ++g) {
            half4 hv, lv;
            #pragma unroll
            for (int j = 0; j < 4; ++j) {
                int r = (g << 2) + j;
                _Float16 h, l;
                fsplit(acc0[r] + (acc1[r] + acc2[r]) * is, h, l);
                hv[j] = h; lv[j] = l;
            }
            int row = grow + (g << 3);
            *(int2*)&d.Dth[(size_t)gcol * 1024 + row] = __builtin_bit_cast(int2, hv);
            *(int2*)&d.Dtl[(size_t)gcol * 1024 + row] = __builtin_bit_cast(int2, lv);
        }
    }
}

// proven i8 XtX body (128x128, BK=128, k-split partials)
__device__ __forceinline__ void xtx_body(const char* __restrict__ xT,
                                         int* __restrict__ Pp, char* smem_,
                                         int i0, int j0, int kz) {
    char (*lds)[2][128][128] = (char (*)[2][128][128])smem_;

    const int tid  = threadIdx.x;
    const int lane = tid & 63;
    const int w    = tid >> 6;
    const int wm   = w >> 1, wn = w & 1;
    const size_t k0 = (size_t)kz << 11;

    const int slab   = w >> 1;
    const int rhalf  = (w & 1) << 6;
    const int rowb   = (slab ? j0 : i0) + rhalf;
    const int lrow   = lane >> 3;
    const int lchunk = (lane & 7) ^ lrow;
    const char* gbase = xT + (size_t)(rowb + lrow) * 8192 + k0 + lchunk * 16;

#define XSTG(kt_, buf_) do {                                                \
        const char* gb = gbase + ((kt_) << 7);                              \
        _Pragma("unroll")                                                   \
        for (int c = 0; c < 8; ++c)                                         \
            gload16(gb + (size_t)(c * 8) * 8192,                            \
                    &lds[buf_][slab][rhalf + c * 8][0]);                    \
    } while (0)

    const int l31 = lane & 31;
    const int kh  = lane >> 5;
    const int r7  = l31 & 7;

    intx16 acc[2][2] = {};

    XSTG(0, 0);
    __syncthreads();

    int cur = 0;
    for (int kt = 0; kt < 16; ++kt) {
        if (kt < 15) XSTG(kt + 1, cur ^ 1);
        #pragma unroll
        for (int kc = 0; kc < 4; ++kc) {
            const int ch = (((kc << 1) | kh) ^ r7) << 4;
            intx4 af[2], bf[2];
            #pragma unroll
            for (int f = 0; f < 2; ++f) {
                af[f] = *(const intx4*)&lds[cur][0][wm * 64 + f * 32 + l31][ch];
                bf[f] = *(const intx4*)&lds[cur][1][wn * 64 + f * 32 + l31][ch];
            }
            #pragma unroll
            for (int fi = 0; fi < 2; ++fi)
                #pragma unroll
                for (int fj = 0; fj < 2; ++fj)
                    acc[fi][fj] = __builtin_amdgcn_mfma_i32_32x32x32_i8(
                        af[fi], bf[fj], acc[fi][fj], 0, 0, 0);
        }
        if (kt < 15) {
            __syncthreads();
            cur ^= 1;
        }
    }
#undef XSTG

    int* Pt = Pp + ((size_t)kz << 20);
    #pragma unroll
    for (int fi = 0; fi < 2; ++fi) {
        #pragma unroll
        for (int fj = 0; fj < 2; ++fj) {
            const int gr0 = i0 + wm * 64 + fi * 32 + (kh << 2);
            const int gc  = j0 + wn * 64 + fj * 32 + l31;
            #pragma unroll
            for (int r = 0; r < 16; ++r) {
                int row = gr0 + (r & 3) + ((r >> 2) << 3);
                Pt[(size_t)row * 1024 + gc] = acc[fi][fj][r];
            }
        }
    }
}

// mega1: z<2 -> gemm(d0/d1); z==2 -> xtx tile
__global__ __launch_bounds__(256) void mega1(GemmDesc d0, GemmDesc d1,
                                             const char* __restrict__ xT,
                                             int* __restrict__ Pp) {
    __shared__ __align__(16) char smem[65536];
    if (blockIdx.z < 2) {
        gemm_body(blockIdx.z ? d1 : d0, smem, blockIdx.x, blockIdx.y);
    } else {
        const int j0 = (blockIdx.x >> 1) << 7;
        const int i0 = (blockIdx.y >> 1) << 7;
        const int kz = ((blockIdx.y & 1) << 1) | (blockIdx.x & 1);
        xtx_body(xT, Pp, smem, i0, j0, kz);
    }
}

// ---------------------------------------------------------------------------
// mega2: y=0 -> vecmat_t (2048 blocks); y=1 -> prepM with inline dv (1024)
__global__ __launch_bounds__(256) void mega2(
        const int* __restrict__ Pp, float* __restrict__ dv,
        _Float16* __restrict__ Mph, _Float16* __restrict__ Mpl,
        const _Float16* __restrict__ W23th, const _Float16* __restrict__ W23tl,
        const float* __restrict__ b1, float* __restrict__ beta1p,
        const _Float16* __restrict__ W3th, const _Float16* __restrict__ W3tl,
        const float* __restrict__ b2, float* __restrict__ beta2) {
    if (blockIdx.y == 0) {     // vecmat role (proven)
        const int which = blockIdx.x >> 10;
        const _Float16* Wh = which ? W3th : W23th;
        const _Float16* Wl = which ? W3tl : W23tl;
        const float*    vv = which ? b2 : b1;
        float*          yy = which ? beta2 : beta1p;
        const float is = 1.0f / 2048.0f;
        int n  = blockIdx.x & 1023;
        int k0 = threadIdx.x << 2;
        int2 th = *(const int2*)&Wh[(size_t)n * 1024 + k0];
        int2 tl = *(const int2*)&Wl[(size_t)n * 1024 + k0];
        half4 h = __builtin_bit_cast(half4, th);
        half4 l = __builtin_bit_cast(half4, tl);
        float4 b = *(const float4*)&vv[k0];
        float acc = ((float)h[0] + (float)l[0] * is) * b.x
                  + ((float)h[1] + (float)l[1] * is) * b.y
                  + ((float)h[2] + (float)l[2] * is) * b.z
                  + ((float)h[3] + (float)l[3] * is) * b.w;
        #pragma unroll
        for (int o = 1; o < 64; o <<= 1) acc += __shfl_xor(acc, o, 64);
        __shared__ float red[4];
        if ((threadIdx.x & 63) == 0) red[threadIdx.x >> 6] = acc;
        __syncthreads();
        if (threadIdx.x == 0) yy[n] = red[0] + red[1] + red[2] + red[3];
        return;
    }
    if (blockIdx.x >= 1024) return;
    // prepM role: sum partials, inline dv, scale+split (proven math)
    const float s1 = 1.f / 3.f, s3 = 1.f / 27.f, s5 = 1.f / 243.f;
    size_t i = ((size_t)blockIdx.x * 256 + threadIdx.x) << 2;
    int row = (int)(i >> 10);
    int cb  = (int)(i & 1023);
    int4 p0 = *(const int4*)&Pp[i];
    int4 p1 = *(const int4*)&Pp[(1 << 20) + i];
    int4 p2 = *(const int4*)&Pp[2 * (size_t)(1 << 20) + i];
    int4 p3 = *(const int4*)&Pp[3 * (size_t)(1 << 20) + i];
    float m[4] = {(float)(p0.x + p1.x + p2.x + p3.x),
                  (float)(p0.y + p1.y + p2.y + p3.y),
                  (float)(p0.z + p1.z + p2.z + p3.z),
                  (float)(p0.w + p1.w + p2.w + p3.w)};
    auto diag4 = [&](int c) -> float {
        size_t o = (size_t)c * 1025;
        return (float)(Pp[o] + Pp[(1 << 20) + o]
                     + Pp[2 * (size_t)(1 << 20) + o] + Pp[3 * (size_t)(1 << 20) + o]);
    };
    float dr = rsqrtf(diag4(row) + 1.0f);
    float d2 = dr * dr;
    float wg = s3 * d2;
    float wc = dr * (s1 * d2 * d2 + s3 * d2 + s5);
    float dda[4];
    #pragma unroll
    for (int t = 0; t < 4; ++t) dda[t] = rsqrtf(diag4(cb + t) + 1.0f);
    half4 h, l;
    #pragma unroll
    for (int t = 0; t < 4; ++t) {
        float v = m[t] * dda[t] * wg + ((cb + t == row) ? wc : 0.f);
        _Float16 hh, ll;
        fsplit(v, hh, ll);
        h[t] = hh; l[t] = ll;
    }
    *(int2*)&Mph[i] = __builtin_bit_cast(int2, h);
    *(int2*)&Mpl[i] = __builtin_bit_cast(int2, l);
    if (cb == (row & ~3)) dv[row] = dr;   // one writer per row
}

// ---------------------------------------------------------------------------
__global__ __launch_bounds__(256) void final_out(const float* __restrict__ H,
                                                 const int* __restrict__ idx,
                                                 const float* __restrict__ dv,
                                                 const float* __restrict__ beta1p,
                                                 const float* __restrict__ beta2,
                                                 const float* __restrict__ b3,
                                                 float* __restrict__ out) {
    const int r = blockIdx.x;
    __shared__ int   sc[KF];
    __shared__ float sd[KF];
    if (threadIdx.x < KF) {
        int c = idx[r * KF + threadIdx.x];
        sc[threadIdx.x] = c;
        sd[threadIdx.x] = dv[c];
    }
    __syncthreads();

    const float s1 = 1.f / 3.f, s2 = 1.f / 9.f, s3 = 1.f / 27.f, s4 = 1.f / 81.f;

    float p = 0.f, q = 0.f, sum2 = 0.f;
    #pragma unroll
    for (int i = 0; i < KF; ++i) {
        float dd = sd[i];
        p += dd;
        sum2 += dd * dd;
        q += dd * dd * dd;
    }
    float u  = (float)KF - sum2;
    float g1 = s2 * u + s1 * q + s3 * p + s4;
    float g2 = s1 * p + s2;

    int j = threadIdx.x << 2;
    float4 bb1 = *(const float4*)&beta1p[j];
    float4 bb2 = *(const float4*)&beta2[j];
    float4 b3v = *(const float4*)&b3[j];
    floatx4 acc;
    acc.x = g1 * bb1.x + g2 * bb2.x + b3v.x;
    acc.y = g1 * bb1.y + g2 * bb2.y + b3v.y;
    acc.z = g1 * bb1.z + g2 * bb2.z + b3v.z;
    acc.w = g1 * bb1.w + g2 * bb2.w + b3v.w;

    #pragma unroll
    for (int i = 0; i < KF; ++i) {
        float4 h = *(const float4*)&H[(size_t)sc[i] * 1024 + j];
        acc.x += h.x;
        acc.y += h.y;
        acc.z += h.z;
        acc.w += h.w;
    }
    __builtin_nontemporal_store(acc, (floatx4*)&out[(size_t)r * 1024 + j]);
}

// ---------------------------------------------------------------------------
extern "C" void kernel_launch(void* const* d_in, const int* in_sizes, int n_in,
                              void* d_out, int out_size, void* d_ws, size_t ws_size,
                              hipStream_t stream) {
    const int*   x   = (const int*)d_in[0];
    const float* emb = (const float*)d_in[1];
    const float* Ws  = (const float*)d_in[2];
    const float* bsv = (const float*)d_in[3];
    float* out = (float*)d_out;

    char* ws = (char*)d_ws;
    const size_t MB = 1 << 20;
    int*   idx    = (int*)(ws);                 // 256 KB
    float* dv     = (float*)(ws + 0x40000);     // 4 KB
    float* beta1p = (float*)(ws + 0x41000);
    float* beta2  = (float*)(ws + 0x42000);
    char*  xT     = (char*)(ws + 1 * MB);       // 8 MB
    int*   Pp     = (int*)(ws + 9 * MB);        // 16 MB (4 x i32 partials)
    _Float16* Eh    = (_Float16*)(ws + 25 * MB);
    _Float16* El    = (_Float16*)(ws + 27 * MB);
    _Float16* W1th  = (_Float16*)(ws + 29 * MB);
    _Float16* W1tl  = (_Float16*)(ws + 31 * MB);
    _Float16* W2h   = (_Float16*)(ws + 33 * MB);
    _Float16* W2l   = (_Float16*)(ws + 35 * MB);
    _Float16* W3th  = (_Float16*)(ws + 37 * MB);
    _Float16* W3tl  = (_Float16*)(ws + 39 * MB);
    _Float16* Mph   = (_Float16*)(ws + 41 * MB);
    _Float16* Mpl   = (_Float16*)(ws + 43 * MB);
    _Float16* Ath   = (_Float16*)(ws + 45 * MB);
    _Float16* Atl   = (_Float16*)(ws + 47 * MB);
    _Float16* W23th = (_Float16*)(ws + 49 * MB);
    _Float16* W23tl = (_Float16*)(ws + 51 * MB);
    _Float16* Th    = (_Float16*)(ws + 53 * MB);
    _Float16* Tl    = (_Float16*)(ws + 55 * MB);
    float*    Hm    = (float*)(ws + 57 * MB);
    char*  xB     = (char*)(ws + 61 * MB);      // 8 MB

    const float* W1 = Ws;
    const float* W2 = Ws + 1024 * 1024;
    const float* W3 = Ws + 2 * 1024 * 1024;
    const float* b1 = bsv;
    const float* b2 = bsv + 1024;
    const float* b3 = bsv + 2048;

    // 1: x -> idx + xB
    pack_extract<<<N_ROWS / 4, 256, 0, stream>>>(x, idx, xB);

    // 2: transpose + all weight splits
    prepT<<<dim3(1024, 5), 256, 0, stream>>>(xB, xT, emb, W1, W2, W3,
        Eh, El, W1th, W1tl, W2h, W2l, W3th, W3tl);

    // 3: S1a + S1b GEMMs (z=0,1) + XtX i8 (z=2), one dispatch
    GemmDesc dS1a = {Eh, El, W1th, W1tl, nullptr, nullptr, nullptr, Ath, Atl};
    GemmDesc dS1b = {W2h, W2l, W3th, W3tl, nullptr, nullptr, nullptr, W23th, W23tl};
    mega1<<<dim3(16, 16, 3), 256, 0, stream>>>(dS1a, dS1b, xT, Pp);

    // 4: beta vecmats + prepM (incl dv)
    mega2<<<dim3(2048, 2), 256, 0, stream>>>(Pp, dv, Mph, Mpl,
        W23th, W23tl, b1, beta1p, W3th, W3tl, b2, beta2);

    // 5: S2 = M' @ A (natural split out)
    GemmDesc dS2 = {Mph, Mpl, Ath, Atl, nullptr, Th, Tl, nullptr, nullptr};
    mega1<<<dim3(16, 16, 1), 256, 0, stream>>>(dS2, dS2, xT, Pp);

    // 6: S3 = T @ W23 (f32 out)
    GemmDesc dS3 = {Th, Tl, W23th, W23tl, Hm, nullptr, nullptr, nullptr, nullptr};
    mega1<<<dim3(16, 16, 1), 256, 0, stream>>>(dS3, dS3, xT, Pp);

    // 7: gather + betas
    final_out<<<N_ROWS, 256, 0, stream>>>(Hm, idx, dv, beta1p, beta2, b3, out);
}

// Round 15
// 117.663 us; speedup vs baseline: 1.1738x; 1.1738x over previous
//
#include <hip/hip_runtime.h>

#define N_ROWS 8192
#define IN_DIM 1024
#define KF     8

typedef _Float16 half8 __attribute__((ext_vector_type(8)));
typedef _Float16 half4 __attribute__((ext_vector_type(4)));
typedef float    floatx4 __attribute__((ext_vector_type(4)));
typedef float    floatx16 __attribute__((ext_vector_type(16)));

__device__ __forceinline__ half8 ld_half8(const _Float16* p) {
    int4 t = *(const int4*)p;
    return __builtin_bit_cast(half8, t);
}
__device__ __forceinline__ void fsplit(float v, _Float16& h, _Float16& l) {
    _Float16 x = (_Float16)v;
    h = x;
    l = (_Float16)((v - (float)x) * 2048.0f);
}
__device__ __forceinline__ void gload16(const void* g, void* l) {
    __builtin_amdgcn_global_load_lds(
        (const __attribute__((address_space(1))) void*)g,
        (__attribute__((address_space(3))) void*)l,
        16, 0, 0);
}

// ---------------------------------------------------------------------------
__global__ void zero_ws(float* __restrict__ Mcnt) {
    size_t i = ((size_t)blockIdx.x * 256 + threadIdx.x) << 2;
    floatx4 z = {0.f, 0.f, 0.f, 0.f};
    *(floatx4*)&Mcnt[i] = z;
}

// ---------------------------------------------------------------------------
// fused: extract per-row indices + upper-triangle co-occurrence pairs.
// Diagonal U[c][c] doubles as the per-feature count.
__global__ void extract_build(const int* __restrict__ x,
                              int* __restrict__ idx,
                              float* __restrict__ M) {
    const int wv   = threadIdx.x >> 6;
    const int r    = blockIdx.x * 4 + wv;
    const int lane = threadIdx.x & 63;
    const int* row = x + (size_t)r * IN_DIM;

    __shared__ int cols[4][KF];

    int vals[16];
    #pragma unroll
    for (int j = 0; j < 4; ++j) {
        int4 v = ((const int4*)row)[lane * 4 + j];
        vals[j * 4 + 0] = v.x;
        vals[j * 4 + 1] = v.y;
        vals[j * 4 + 2] = v.z;
        vals[j * 4 + 3] = v.w;
    }
    int c = 0;
    #pragma unroll
    for (int j = 0; j < 16; ++j) c += (vals[j] != 0);

    int s = c;
    #pragma unroll
    for (int o = 1; o < 64; o <<= 1) {
        int t = __shfl_up(s, o, 64);
        if (lane >= o) s += t;
    }
    int pos = s - c;

    #pragma unroll
    for (int j = 0; j < 16; ++j) {
        if (vals[j] != 0) {
            int col = lane * 16 + j;
            if (pos < KF) {
                idx[r * KF + pos] = col;
                cols[wv][pos] = col;
            }
            pos++;
        }
    }
    __syncthreads();
    int i = lane >> 3, j = lane & 7;
    if (i <= j) {
        int ci = cols[wv][i];
        int cj = cols[wv][j];
        atomicAdd(&M[ci * IN_DIM + cj], 1.0f);
    }
}

// ---------------------------------------------------------------------------
// prep: y = task: 0 split E, 1 split W2, 2 transp W1, 3 transp W3,
//       4: M' = diag(wG)*(U+U^T)*diag(d) + diag(wC), split (diag(U) = counts)
__global__ __launch_bounds__(256) void prep(
        const float* __restrict__ emb, const float* __restrict__ W1,
        const float* __restrict__ W2, const float* __restrict__ W3,
        const float* __restrict__ Mc,
        _Float16* __restrict__ Eh, _Float16* __restrict__ El,
        _Float16* __restrict__ W1th, _Float16* __restrict__ W1tl,
        _Float16* __restrict__ W2h, _Float16* __restrict__ W2l,
        _Float16* __restrict__ W3th, _Float16* __restrict__ W3tl,
        _Float16* __restrict__ Mph, _Float16* __restrict__ Mpl) {
    const int task = blockIdx.y;
    const int bx   = blockIdx.x;

    if (task <= 1) {
        const float* S = task ? W2 : emb;
        _Float16* Hp = task ? W2h : Eh;
        _Float16* Lp = task ? W2l : El;
        size_t i = ((size_t)bx * 256 + threadIdx.x) << 2;
        float4 v = *(const float4*)&S[i];
        float vv[4] = {v.x, v.y, v.z, v.w};
        half4 h, l;
        #pragma unroll
        for (int j = 0; j < 4; ++j) { _Float16 hh, ll; fsplit(vv[j], hh, ll); h[j] = hh; l[j] = ll; }
        *(int2*)&Hp[i] = __builtin_bit_cast(int2, h);
        *(int2*)&Lp[i] = __builtin_bit_cast(int2, l);
        return;
    }
    if (task <= 3) {
        if (bx >= 256) return;
        const float* S = (task == 3) ? W3 : W1;
        _Float16* Hp = (task == 3) ? W3th : W1th;
        _Float16* Lp = (task == 3) ? W3tl : W1tl;
        __shared__ float sh[64][65];
        const int r0 = (bx >> 4) << 6, c0 = (bx & 15) << 6;
        #pragma unroll
        for (int it = 0; it < 4; ++it) {
            int r = (threadIdx.x >> 4) + (it << 4);
            int c = (threadIdx.x & 15) << 2;
            float4 v = *(const float4*)&S[(size_t)(r0 + r) * 1024 + c0 + c];
            sh[r][c] = v.x; sh[r][c + 1] = v.y; sh[r][c + 2] = v.z; sh[r][c + 3] = v.w;
        }
        __syncthreads();
        int nl = threadIdx.x >> 2;
        #pragma unroll
        for (int cc = 0; cc < 2; ++cc) {
            int kq = ((threadIdx.x & 3) << 4) + (cc << 3);
            half8 h, l;
            #pragma unroll
            for (int j = 0; j < 8; ++j) {
                _Float16 hh, ll;
                fsplit(sh[kq + j][nl], hh, ll);
                h[j] = hh; l[j] = ll;
            }
            *(int4*)&Hp[(size_t)(c0 + nl) * 1024 + r0 + kq] = __builtin_bit_cast(int4, h);
            *(int4*)&Lp[(size_t)(c0 + nl) * 1024 + r0 + kq] = __builtin_bit_cast(int4, l);
        }
        return;
    }
    // task 4: tiled symmetrize + scale + split; counts from diag(U)
    if (bx >= 256) return;
    const int i0 = (bx >> 4) << 6;
    const int j0 = (bx & 15) << 6;
    __shared__ float tU[64][65];
    __shared__ float ddi[64], ddj[64];
    #pragma unroll
    for (int it = 0; it < 4; ++it) {
        int r = (threadIdx.x >> 4) + (it << 4);
        int c = (threadIdx.x & 15) << 2;
        float4 v = *(const float4*)&Mc[(size_t)(j0 + r) * 1024 + i0 + c];
        tU[r][c] = v.x; tU[r][c + 1] = v.y; tU[r][c + 2] = v.z; tU[r][c + 3] = v.w;
    }
    if (threadIdx.x < 64) {
        int c = i0 + threadIdx.x;
        ddi[threadIdx.x] = rsqrtf(Mc[(size_t)c * 1025] + 1.0f);
    } else if (threadIdx.x < 128) {
        int t = threadIdx.x - 64;
        int c = j0 + t;
        ddj[t] = rsqrtf(Mc[(size_t)c * 1025] + 1.0f);
    }
    __syncthreads();

    const float s1 = 1.f / 3.f, s3 = 1.f / 27.f, s5 = 1.f / 243.f;
    const int ii = threadIdx.x >> 2;
    const int gi = i0 + ii;
    float dr = ddi[ii];
    float d2 = dr * dr;
    float wg = s3 * d2;
    float wc = dr * (s1 * d2 * d2 + s3 * d2 + s5);

    #pragma unroll
    for (int q = 0; q < 4; ++q) {
        int jj = ((threadIdx.x & 3) << 4) + (q << 2);
        size_t gidx = (size_t)gi * 1024 + j0 + jj;
        float4 un = *(const float4*)&Mc[gidx];
        float uv[4] = {un.x, un.y, un.z, un.w};
        half4 h, l;
        #pragma unroll
        for (int t = 0; t < 4; ++t) {
            int gj = j0 + jj + t;
            float m = (gi == gj) ? uv[t] : (uv[t] + tU[jj + t][ii]);
            float v = m * ddj[jj + t] * wg + ((gi == gj) ? wc : 0.f);
            _Float16 hh, ll;
            fsplit(v, hh, ll);
            h[t] = hh; l[t] = ll;
        }
        *(int2*)&Mph[gidx] = __builtin_bit_cast(int2, h);
        *(int2*)&Mpl[gidx] = __builtin_bit_cast(int2, l);
    }
}

// ---------------------------------------------------------------------------
// proven split-f16 MFMA GEMM: 64x64 tile, 4 waves, 32x32x16 frags, 3 chains.
struct GemmDesc {
    const _Float16 *Ah, *Al;
    const _Float16 *Bh, *Bl;
    float* Df;
    _Float16 *Dnh, *Dnl;
    _Float16 *Dth, *Dtl;
};

__global__ __launch_bounds__(256) void gemm_split(GemmDesc d0, GemmDesc d1)
{
    GemmDesc d = blockIdx.z ? d1 : d0;
    __shared__ _Float16 lds[2][4][64][64];

    const int tid  = threadIdx.x;
    const int lane = tid & 63;
    const int w    = tid >> 6;
    const int wm   = w >> 1, wn = w & 1;
    const int brow = blockIdx.y << 6;
    const int bcol = blockIdx.x << 6;

    const _Float16* gsrc = (w == 0) ? d.Ah : (w == 1) ? d.Al : (w == 2) ? d.Bh : d.Bl;
    const int rowbase = (w < 2) ? brow : bcol;
    const int swz = (((lane & 7) ^ ((lane >> 3) & 7)) << 3);
    const _Float16* gbase = gsrc + (size_t)(rowbase + (lane >> 3)) * 1024 + swz;

#define STAGE(kt_, buf_) do {                                              \
        _Float16* lb = &lds[buf_][w][0][0];                                \
        const _Float16* gb = gbase + ((kt_) << 6);                         \
        _Pragma("unroll")                                                  \
        for (int c = 0; c < 8; ++c)                                        \
            gload16(gb + ((size_t)(c << 3) << 10), lb + (c << 9));         \
    } while (0)

    const int l31  = lane & 31;
    const int kh   = lane >> 5;
    const int arow = (wm << 5) + l31;
    const int brw  = (wn << 5) + l31;
    const int r7   = l31 & 7;

    floatx16 acc0 = {};
    floatx16 acc1 = {};
    floatx16 acc2 = {};

    STAGE(0, 0);
    __syncthreads();

    int cur = 0;
    for (int kt = 0; kt < 16; ++kt) {
        if (kt < 15) STAGE(kt + 1, cur ^ 1);
        const _Float16* pa_h = &lds[cur][0][arow][0];
        const _Float16* pa_l = &lds[cur][1][arow][0];
        const _Float16* pb_h = &lds[cur][2][brw][0];
        const _Float16* pb_l = &lds[cur][3][brw][0];
        #pragma unroll
        for (int kc = 0; kc < 4; ++kc) {
            int ca = ((((kc << 1) | kh) ^ r7) << 3);
            half8 ah = ld_half8(pa_h + ca);
            half8 al = ld_half8(pa_l + ca);
            half8 bh = ld_half8(pb_h + ca);
            half8 bl = ld_half8(pb_l + ca);
            acc0 = __builtin_amdgcn_mfma_f32_32x32x16_f16(ah, bh, acc0, 0, 0, 0);
            acc1 = __builtin_amdgcn_mfma_f32_32x32x16_f16(ah, bl, acc1, 0, 0, 0);
            acc2 = __builtin_amdgcn_mfma_f32_32x32x16_f16(al, bh, acc2, 0, 0, 0);
        }
        if (kt < 15) {
            __syncthreads();
            cur ^= 1;
        }
    }
#undef STAGE

    const float is = 1.0f / 2048.0f;
    const int grow = brow + (wm << 5) + (kh << 2);
    const int gcol = bcol + (wn << 5) + l31;

    if (d.Df) {
        #pragma unroll
        for (int r = 0; r < 16; ++r) {
            int row = grow + (r & 3) + ((r >> 2) << 3);
            d.Df[(size_t)row * 1024 + gcol] = acc0[r] + (acc1[r] + acc2[r]) * is;
        }
    }
    if (d.Dnh) {
        #pragma unroll
        for (int r = 0; r < 16; ++r) {
            int row = grow + (r & 3) + ((r >> 2) << 3);
            _Float16 h, l;
            fsplit(acc0[r] + (acc1[r] + acc2[r]) * is, h, l);
            d.Dnh[(size_t)row * 1024 + gcol] = h;
            d.Dnl[(size_t)row * 1024 + gcol] = l;
        }
    }
    if (d.Dth) {
        #pragma unroll
        for (int g = 0; g < 4; ++g) {
            half4 hv, lv;
            #pragma unroll
            for (int j = 0; j < 4; ++j) {
                int r = (g << 2) + j;
                _Float16 h, l;
                fsplit(acc0[r] + (acc1[r] + acc2[r]) * is, h, l);
                hv[j] = h; lv[j] = l;
            }
            int row = grow + (g << 3);
            *(int2*)&d.Dth[(size_t)gcol * 1024 + row] = __builtin_bit_cast(int2, hv);
            *(int2*)&d.Dtl[(size_t)gcol * 1024 + row] = __builtin_bit_cast(int2, lv);
        }
    }
}

// ---------------------------------------------------------------------------
// k-split-2 variant for S2: grid (16,16,2), z = K-half; f32 partial output.
// Body identical to gemm_split except kbeg offset, 8 kt iters, f32-only epilogue.
__global__ __launch_bounds__(256) void gemm_ks2_f32(
        const _Float16* __restrict__ Ah, const _Float16* __restrict__ Al,
        const _Float16* __restrict__ Bh, const _Float16* __restrict__ Bl,
        float* __restrict__ Pp)
{
    __shared__ _Float16 lds[2][4][64][64];

    const int tid  = threadIdx.x;
    const int lane = tid & 63;
    const int w    = tid >> 6;
    const int wm   = w >> 1, wn = w & 1;
    const int brow = blockIdx.y << 6;
    const int bcol = blockIdx.x << 6;
    const int kbeg = blockIdx.z << 9;        // 0 or 512

    const _Float16* gsrc = (w == 0) ? Ah : (w == 1) ? Al : (w == 2) ? Bh : Bl;
    const int rowbase = (w < 2) ? brow : bcol;
    const int swz = (((lane & 7) ^ ((lane >> 3) & 7)) << 3);
    const _Float16* gbase = gsrc + (size_t)(rowbase + (lane >> 3)) * 1024 + kbeg + swz;

#define STAGE(kt_, buf_) do {                                              \
        _Float16* lb = &lds[buf_][w][0][0];                                \
        const _Float16* gb = gbase + ((kt_) << 6);                         \
        _Pragma("unroll")                                                  \
        for (int c = 0; c < 8; ++c)                                        \
            gload16(gb + ((size_t)(c << 3) << 10), lb + (c << 9));         \
    } while (0)

    const int l31  = lane & 31;
    const int kh   = lane >> 5;
    const int arow = (wm << 5) + l31;
    const int brw  = (wn << 5) + l31;
    const int r7   = l31 & 7;

    floatx16 acc0 = {};
    floatx16 acc1 = {};
    floatx16 acc2 = {};

    STAGE(0, 0);
    __syncthreads();

    int cur = 0;
    for (int kt = 0; kt < 8; ++kt) {
        if (kt < 7) STAGE(kt + 1, cur ^ 1);
        const _Float16* pa_h = &lds[cur][0][arow][0];
        const _Float16* pa_l = &lds[cur][1][arow][0];
        const _Float16* pb_h = &lds[cur][2][brw][0];
        const _Float16* pb_l = &lds[cur][3][brw][0];
        #pragma unroll
        for (int kc = 0; kc < 4; ++kc) {
            int ca = ((((kc << 1) | kh) ^ r7) << 3);
            half8 ah = ld_half8(pa_h + ca);
            half8 al = ld_half8(pa_l + ca);
            half8 bh = ld_half8(pb_h + ca);
            half8 bl = ld_half8(pb_l + ca);
            acc0 = __builtin_amdgcn_mfma_f32_32x32x16_f16(ah, bh, acc0, 0, 0, 0);
            acc1 = __builtin_amdgcn_mfma_f32_32x32x16_f16(ah, bl, acc1, 0, 0, 0);
            acc2 = __builtin_amdgcn_mfma_f32_32x32x16_f16(al, bh, acc2, 0, 0, 0);
        }
        if (kt < 7) {
            __syncthreads();
            cur ^= 1;
        }
    }
#undef STAGE

    const float is = 1.0f / 2048.0f;
    const int grow = brow + (wm << 5) + (kh << 2);
    const int gcol = bcol + (wn << 5) + l31;
    float* Pt = Pp + ((size_t)blockIdx.z << 20);
    #pragma unroll
    for (int r = 0; r < 16; ++r) {
        int row = grow + (r & 3) + ((r >> 2) << 3);
        Pt[(size_t)row * 1024 + gcol] = acc0[r] + (acc1[r] + acc2[r]) * is;
    }
}

// ---------------------------------------------------------------------------
// combineT: y=0 -> T = split(P0+P1); y=1 -> beta1p = b1@W23; y=2 -> beta2 = b2@W3
__global__ __launch_bounds__(256) void combineT(
        const float* __restrict__ Pp,
        _Float16* __restrict__ Th, _Float16* __restrict__ Tl,
        const _Float16* __restrict__ W23th, const _Float16* __restrict__ W23tl,
        const float* __restrict__ b1, float* __restrict__ beta1p,
        const _Float16* __restrict__ W3th, const _Float16* __restrict__ W3tl,
        const float* __restrict__ b2, float* __restrict__ beta2) {
    if (blockIdx.y == 0) {
        size_t i = ((size_t)blockIdx.x * 256 + threadIdx.x) << 2;
        float4 a = *(const float4*)&Pp[i];
        float4 b = *(const float4*)&Pp[(1 << 20) + i];
        float vv[4] = {a.x + b.x, a.y + b.y, a.z + b.z, a.w + b.w};
        half4 h, l;
        #pragma unroll
        for (int j = 0; j < 4; ++j) { _Float16 hh, ll; fsplit(vv[j], hh, ll); h[j] = hh; l[j] = ll; }
        *(int2*)&Th[i] = __builtin_bit_cast(int2, h);
        *(int2*)&Tl[i] = __builtin_bit_cast(int2, l);
        return;
    }
    // vecmat roles (proven body)
    const int which = blockIdx.y - 1;
    const _Float16* Wh = which ? W3th : W23th;
    const _Float16* Wl = which ? W3tl : W23tl;
    const float*    vv = which ? b2 : b1;
    float*          yy = which ? beta2 : beta1p;
    const float is = 1.0f / 2048.0f;
    int n  = blockIdx.x;
    int k0 = threadIdx.x << 2;
    int2 th = *(const int2*)&Wh[(size_t)n * 1024 + k0];
    int2 tl = *(const int2*)&Wl[(size_t)n * 1024 + k0];
    half4 h = __builtin_bit_cast(half4, th);
    half4 l = __builtin_bit_cast(half4, tl);
    float4 b = *(const float4*)&vv[k0];
    float acc = ((float)h[0] + (float)l[0] * is) * b.x
              + ((float)h[1] + (float)l[1] * is) * b.y
              + ((float)h[2] + (float)l[2] * is) * b.z
              + ((float)h[3] + (float)l[3] * is) * b.w;
    #pragma unroll
    for (int o = 1; o < 64; o <<= 1) acc += __shfl_xor(acc, o, 64);
    __shared__ float red[4];
    if ((threadIdx.x & 63) == 0) red[threadIdx.x >> 6] = acc;
    __syncthreads();
    if (threadIdx.x == 0) yy[n] = red[0] + red[1] + red[2] + red[3];
}

// ---------------------------------------------------------------------------
// out[r] = sum_i H[c_i] + g1*beta1p + g2*beta2 + b3 ; counts from diag(U)
__global__ __launch_bounds__(256) void final_out(const float* __restrict__ H,
                                                 const int* __restrict__ idx,
                                                 const float* __restrict__ Mc,
                                                 const float* __restrict__ beta1p,
                                                 const float* __restrict__ beta2,
                                                 const float* __restrict__ b3,
                                                 float* __restrict__ out) {
    const int r = blockIdx.x;
    __shared__ int   sc[KF];
    __shared__ float sd[KF];
    if (threadIdx.x < KF) {
        int c = idx[r * KF + threadIdx.x];
        sc[threadIdx.x] = c;
        sd[threadIdx.x] = rsqrtf(Mc[(size_t)c * 1025] + 1.0f);
    }
    __syncthreads();

    const float s1 = 1.f / 3.f, s2 = 1.f / 9.f, s3 = 1.f / 27.f, s4 = 1.f / 81.f;

    float p = 0.f, q = 0.f, sum2 = 0.f;
    #pragma unroll
    for (int i = 0; i < KF; ++i) {
        float dd = sd[i];
        p += dd;
        sum2 += dd * dd;
        q += dd * dd * dd;
    }
    float u  = (float)KF - sum2;
    float g1 = s2 * u + s1 * q + s3 * p + s4;
    float g2 = s1 * p + s2;

    int j = threadIdx.x << 2;
    float4 bb1 = *(const float4*)&beta1p[j];
    float4 bb2 = *(const float4*)&beta2[j];
    float4 b3v = *(const float4*)&b3[j];
    floatx4 acc;
    acc.x = g1 * bb1.x + g2 * bb2.x + b3v.x;
    acc.y = g1 * bb1.y + g2 * bb2.y + b3v.y;
    acc.z = g1 * bb1.z + g2 * bb2.z + b3v.z;
    acc.w = g1 * bb1.w + g2 * bb2.w + b3v.w;

    #pragma unroll
    for (int i = 0; i < KF; ++i) {
        float4 h = *(const float4*)&H[(size_t)sc[i] * 1024 + j];
        acc.x += h.x;
        acc.y += h.y;
        acc.z += h.z;
        acc.w += h.w;
    }
    __builtin_nontemporal_store(acc, (floatx4*)&out[(size_t)r * 1024 + j]);
}

// ---------------------------------------------------------------------------
extern "C" void kernel_launch(void* const* d_in, const int* in_sizes, int n_in,
                              void* d_out, int out_size, void* d_ws, size_t ws_size,
                              hipStream_t stream) {
    const int*   x   = (const int*)d_in[0];
    const float* emb = (const float*)d_in[1];
    const float* Ws  = (const float*)d_in[2];
    const float* bsv = (const float*)d_in[3];
    float* out = (float*)d_out;

    char* ws = (char*)d_ws;
    const size_t MB = 1 << 20;
    int*   idx    = (int*)(ws);
    float* beta1p = (float*)(ws + 0x44000);
    float* beta2  = (float*)(ws + 0x45000);
    float* Mcnt   = (float*)(ws + 1 * MB);
    _Float16* Eh    = (_Float16*)(ws + 5 * MB);
    _Float16* El    = (_Float16*)(ws + 7 * MB);
    _Float16* W1th  = (_Float16*)(ws + 9 * MB);
    _Float16* W1tl  = (_Float16*)(ws + 11 * MB);
    _Float16* W2h   = (_Float16*)(ws + 13 * MB);
    _Float16* W2l   = (_Float16*)(ws + 15 * MB);
    _Float16* W3th  = (_Float16*)(ws + 17 * MB);
    _Float16* W3tl  = (_Float16*)(ws + 19 * MB);
    _Float16* Mph   = (_Float16*)(ws + 21 * MB);
    _Float16* Mpl   = (_Float16*)(ws + 23 * MB);
    _Float16* Ath   = (_Float16*)(ws + 25 * MB);
    _Float16* Atl   = (_Float16*)(ws + 27 * MB);
    _Float16* W23th = (_Float16*)(ws + 29 * MB);
    _Float16* W23tl = (_Float16*)(ws + 31 * MB);
    _Float16* Th    = (_Float16*)(ws + 33 * MB);
    _Float16* Tl    = (_Float16*)(ws + 35 * MB);
    float*    Hm    = (float*)(ws + 37 * MB);
    float*    Pp    = (float*)(ws + 41 * MB);   // 8 MB (2 x f32 partials)

    const float* W1 = Ws;
    const float* W2 = Ws + 1024 * 1024;
    const float* W3 = Ws + 2 * 1024 * 1024;
    const float* b1 = bsv;
    const float* b2 = bsv + 1024;
    const float* b3 = bsv + 2048;

    zero_ws<<<1024, 256, 0, stream>>>(Mcnt);

    extract_build<<<N_ROWS / 4, 256, 0, stream>>>(x, idx, Mcnt);

    prep<<<dim3(1024, 5), 256, 0, stream>>>(emb, W1, W2, W3, Mcnt,
        Eh, El, W1th, W1tl, W2h, W2l, W3th, W3tl, Mph, Mpl);

    // S1a: At = (E @ W1)^T ; S1b: W23t = (W2 @ W3)^T  -- one dispatch
    GemmDesc dS1a = {Eh, El, W1th, W1tl, nullptr, nullptr, nullptr, Ath, Atl};
    GemmDesc dS1b = {W2h, W2l, W3th, W3tl, nullptr, nullptr, nullptr, W23th, W23tl};
    gemm_split<<<dim3(16, 16, 2), 256, 0, stream>>>(dS1a, dS1b);

    // S2 (k-split 2): Pp[z] = partial of M' @ A
    gemm_ks2_f32<<<dim3(16, 16, 2), 256, 0, stream>>>(Mph, Mpl, Ath, Atl, Pp);

    // combineT (T = split(P0+P1)) + both beta vecmats in one dispatch
    combineT<<<dim3(1024, 3), 256, 0, stream>>>(Pp, Th, Tl,
        W23th, W23tl, b1, beta1p, W3th, W3tl, b2, beta2);

    // S3: H = T @ W23  (f32 out)
    GemmDesc dS3 = {Th, Tl, W23th, W23tl, Hm, nullptr, nullptr, nullptr, nullptr};
    gemm_split<<<dim3(16, 16, 1), 256, 0, stream>>>(dS3, dS3);

    final_out<<<N_ROWS, 256, 0, stream>>>(Hm, idx, Mcnt, beta1p, beta2, b3, out);
}